// Round 4
// baseline (41.506 us; speedup 1.0000x reference)
//
#include <hip/hip_runtime.h>

#define DI __device__ __forceinline__

constexpr int BATCH = 256;
constexpr int INF   = 4096;   // in_features
constexpr int NGRP  = 1024;   // INF/4
constexpr int MOUT  = 4096;   // out_features

constexpr int BM = 64, BN = 64;         // block output tile
constexpr int WK = 512;                 // K-slice per wave (8 waves cover 4096)
constexpr int NH = WK / 32;             // 16 half-steps of k=32
constexpr int RP = 68;                  // padded LDS row stride (f32), 16B-aligned

using bf16x8 = __attribute__((ext_vector_type(8))) short;
using f32x4  = __attribute__((ext_vector_type(4))) float;

// D4 half-codebook, stored as 2x the actual values (int8); actual = v * 0.5
__device__ __constant__ signed char D4_I8[512] = {
     0, 0, 0, 0,  -4, 0, 0, 0,  -2,-2,-2,-2,  -2,-2,-2, 0,  -2,-2,-2, 2,  -2,-2, 0,-2,  -2,-2, 0, 0,  -2,-2, 0, 2,
    -2,-2, 2,-2,  -2,-2, 2, 0,  -2,-2, 2, 2,  -2, 0,-2,-2,  -2, 0,-2, 0,  -2, 0,-2, 2,  -2, 0, 0,-2,  -2, 0, 0, 0,
    -2, 0, 0, 2,  -2, 0, 2,-2,  -2, 0, 2, 0,  -2, 0, 2, 2,  -2, 2,-2,-2,  -2, 2,-2, 0,  -2, 2,-2, 2,  -2, 2, 0,-2,
    -2, 2, 0, 0,  -2, 2, 0, 2,  -2, 2, 2,-2,  -2, 2, 2, 0,  -2, 2, 2, 2,   0,-4, 0, 0,   0,-2,-2,-2,   0,-2,-2, 0,
     0,-2,-2, 2,   0,-2, 0,-2,   0,-2, 0, 0,   0,-2, 0, 2,   0,-2, 2,-2,   0,-2, 2, 0,   0,-2, 2, 2,   0, 0,-4, 0,
     0, 0,-2,-2,   0, 0,-2, 0,   0, 0,-2, 2,   0, 0, 0,-4,   0, 0, 0,-2,
    -3,-1,-3,-1,  -3,-1,-3, 1,  -3,-1,-1,-3,  -3,-1,-1,-1,  -3,-1,-1, 1,  -3,-1,-1, 3,  -3,-1, 1,-3,  -3,-1, 1,-1,
    -3,-1, 1, 1,  -3,-1, 1, 3,  -3,-1, 3,-1,  -3,-1, 3, 1,  -3, 1,-3,-1,  -3, 1,-3, 1,  -3, 1,-1,-3,  -3, 1,-1,-1,
    -3, 1,-1, 1,  -3, 1,-1, 3,  -3, 1, 1,-3,  -3, 1, 1,-1,  -3, 1, 1, 1,  -3, 1, 1, 3,  -3, 1, 3,-1,  -3, 1, 3, 1,
    -3, 3,-1,-1,  -3, 3, 1,-1,  -3, 3, 1, 1,  -1,-3,-3,-1,  -1,-3,-3, 1,  -1,-3,-1,-3,  -1,-3,-1,-1,  -1,-3,-1, 1,
    -1,-3,-1, 3,  -1,-3, 1,-3,  -1,-3, 1,-1,  -1,-3, 1, 1,  -1,-3, 1, 3,  -1,-3, 3,-1,  -1,-3, 3, 1,  -1,-1,-3,-3,
    -1,-1,-3,-1,  -1,-1,-3, 1,  -1,-1,-3, 3,  -1,-1,-1,-3,  -1,-1,-1,-1,  -1,-1,-1, 1,  -1,-1,-1, 3,  -1,-1, 1,-3,
    -1,-1, 1,-1,  -1,-1, 1, 1,  -1,-1, 1, 3,  -1,-1, 3,-3,  -1,-1, 3,-1,  -1,-1, 3, 1,  -1,-1, 3, 3,  -1, 1,-3,-3,
    -1, 1,-3,-1,  -1, 1,-3, 1,  -1, 1,-3, 3,  -1, 1,-1,-3,  -1, 1,-1,-1,  -1, 1,-1, 1,  -1, 1,-1, 3,  -1, 1, 1,-3,
    -1, 1, 1,-1,  -1, 1, 1, 1,  -1, 1, 1, 3,  -1, 1, 3,-3,  -1, 1, 3,-1,  -1, 1, 3, 1,  -1, 1, 3, 3,  -1, 3,-3,-1,
    -1, 3,-3, 1,  -1, 3,-1,-3,  -1, 3,-1,-1,  -1, 3,-1, 1,  -1, 3,-1, 3,  -1, 3, 1,-3,  -1, 3, 1,-1,  -1, 3, 1, 1,
    -1, 3, 1, 3,  -1, 3, 3,-1,  -1, 3, 3, 1
};

DI unsigned short f2bf(float f) {  // f32 -> bf16 bits, round-to-nearest-even
  unsigned int u = __float_as_uint(f);
  u += 0x7fffu + ((u >> 16) & 1u);
  return (unsigned short)(u >> 16);
}

// Build Xs = input * scaleW_DSC * Qscales (bf16) into d_ws.
__global__ __launch_bounds__(256) void prep_kernel(
    const float* __restrict__ inp, const float* __restrict__ sw,
    const float* __restrict__ qs, unsigned short* __restrict__ xs) {
  int i = blockIdx.x * 256 + threadIdx.x;      // group-of-4 index, 262144 total
  int g = i & (NGRP - 1);
  float4 v = reinterpret_cast<const float4*>(inp)[i];
  float4 s = reinterpret_cast<const float4*>(sw)[g];
  float  q = qs[g];
  ushort4 o;
  o.x = f2bf(v.x * s.x * q);
  o.y = f2bf(v.y * s.y * q);
  o.z = f2bf(v.z * s.z * q);
  o.w = f2bf(v.w * s.w * q);
  reinterpret_cast<ushort4*>(xs)[i] = o;
}

// Fused dequant-GEMM, block-local split-K, 3-stage software pipeline:
// Qidxs gathered 2 half-steps ahead, A-fragments 1 ahead, codebook lookups
// for step t+1 issued before step t's MFMA cluster. Partials reduced via
// LDS, output stored once (no atomics).
__global__ __launch_bounds__(512, 2) void gemm_kernel(
    const unsigned short* __restrict__ xs, const int* __restrict__ qidx,
    float* __restrict__ out) {
  __shared__ unsigned long long tbl[256];   // 2 KB, sign-folded bf16x4 codebook
  __shared__ float red[8][BM * RP];         // 8 x 17.4 KB partial tiles

  const int tid  = threadIdx.x;
  const int lane = tid & 63;
  const int wave = tid >> 6;                // 0..7 = k-slice
  const int l15  = lane & 15, l4 = lane >> 4;

  // ---- XCD swizzle: the 4 m-blocks of one n-tile share an XCD so the 4x
  // Qidxs re-read is an L2 hit (2 MB Qidxs region per XCD).
  const int bid = blockIdx.x;               // 0..255
  const int nt  = (bid & 7) * 8 + ((bid >> 3) & 7);   // 0..63
  const int mt  = bid >> 6;                           // 0..3
  const int m0 = mt * BM, n0 = nt * BN;

  // ---- signed codebook table: tbl[i] = 4 packed bf16, tbl[i+128] = -tbl[i]
  if (tid < 256) {
    int r = tid & 127, sg = tid >> 7;
    unsigned long long v = 0;
#pragma unroll
    for (int j = 0; j < 4; ++j) {
      float f = (float)D4_I8[r * 4 + j] * 0.5f;
      unsigned int b = __float_as_uint(f) ^ (sg ? 0x80000000u : 0u);
      v |= (unsigned long long)(b >> 16) << (16 * j);
    }
    tbl[tid] = v;
  }
  __syncthreads();

  // ---- per-lane bases for this wave's k-slice
  const int k0 = wave * WK;
  const unsigned short* ab = xs + (size_t)(m0 + l15) * INF + k0 + l4 * 8;
  const int* qb = qidx + (size_t)(n0 + l15) * NGRP + (k0 >> 2) + l4 * 2;

  f32x4  acc[4][4] = {};
  int2   qbuf[3][4] = {};
  bf16x8 abuf[2][4];
  bf16x8 bbuf[2][4];

  auto qload = [&](int s, int t) {
    if (t < NH)
#pragma unroll
      for (int ni = 0; ni < 4; ++ni)
        qbuf[s][ni] = *reinterpret_cast<const int2*>(
            qb + (size_t)ni * 16 * NGRP + t * 8);
  };
  auto aload = [&](int s, int t) {
    if (t < NH)
#pragma unroll
      for (int mi = 0; mi < 4; ++mi)
        abuf[s][mi] = *reinterpret_cast<const bf16x8*>(
            ab + (size_t)mi * 16 * INF + t * 32);
  };
  auto blook = [&](int s, int qs) {   // 8 ds_read_b64 (indices &255 in-bounds)
#pragma unroll
    for (int ni = 0; ni < 4; ++ni) {
      union { unsigned long long u[2]; bf16x8 v; } c;
      c.u[0] = tbl[qbuf[qs][ni].x & 255];
      c.u[1] = tbl[qbuf[qs][ni].y & 255];
      bbuf[s][ni] = c.v;
    }
  };

  // ---- prologue
  qload(0, 0);
  qload(1, 1);
  aload(0, 0);
  blook(0, 0);

  // ---- pipelined k-loop, fully unrolled (all buffer indices static)
#pragma unroll
  for (int t = 0; t < NH; ++t) {
    qload((t + 2) % 3, t + 2);          // indices, 2 ahead
    aload((t + 1) & 1, t + 1);          // A-fragments, 1 ahead
    blook((t + 1) & 1, (t + 1) % 3);    // LDS lookups for t+1 before MFMAs of t
#pragma unroll
    for (int mi = 0; mi < 4; ++mi)
#pragma unroll
      for (int ni = 0; ni < 4; ++ni)
        acc[mi][ni] = __builtin_amdgcn_mfma_f32_16x16x32_bf16(
            abuf[t & 1][mi], bbuf[t & 1][ni], acc[mi][ni], 0, 0, 0);
  }

  // ---- write this wave's partial tile to LDS
  {
    float* rw = &red[wave][0];
#pragma unroll
    for (int mi = 0; mi < 4; ++mi)
#pragma unroll
      for (int ni = 0; ni < 4; ++ni)
#pragma unroll
        for (int r = 0; r < 4; ++r)
          rw[(mi * 16 + l4 * 4 + r) * RP + ni * 16 + l15] = acc[mi][ni][r];
  }
  __syncthreads();

  // ---- reduce 8 partials, store coalesced float4 (exclusive ownership)
  const int qn = tid & 15;        // n-quad
  const int mr = tid >> 4;        // 0..31
#pragma unroll
  for (int mm = mr; mm < BM; mm += 32) {
    float4 s = make_float4(0.f, 0.f, 0.f, 0.f);
#pragma unroll
    for (int w = 0; w < 8; ++w) {
      float4 p = *reinterpret_cast<const float4*>(&red[w][mm * RP + qn * 4]);
      s.x += p.x; s.y += p.y; s.z += p.z; s.w += p.w;
    }
    *reinterpret_cast<float4*>(
        &out[(size_t)(m0 + mm) * MOUT + n0 + qn * 4]) = s;
  }
}

extern "C" void kernel_launch(void* const* d_in, const int* in_sizes, int n_in,
                              void* d_out, int out_size, void* d_ws, size_t ws_size,
                              hipStream_t stream) {
  const float* inp = (const float*)d_in[0];
  const float* sw  = (const float*)d_in[1];
  const float* qs  = (const float*)d_in[2];
  const int*   qi  = (const int*)d_in[3];
  float* out = (float*)d_out;
  unsigned short* xs = (unsigned short*)d_ws;   // 256*4096 bf16 = 2 MB scratch

  prep_kernel<<<(BATCH * INF / 4) / 256, 256, 0, stream>>>(inp, sw, qs, xs);

  constexpr int GRID = (BATCH / BM) * (MOUT / BN);   // 4 * 64 = 256
  gemm_kernel<<<GRID, 512, 0, stream>>>(xs, qi, out);
}